// Round 7
// baseline (163.178 us; speedup 1.0000x reference)
//
#include <hip/hip_runtime.h>
#include <hip/hip_bf16.h>
#include <cstdint>

#define TB 8
#define TT 2048
#define TC 1024
#define TH 64

typedef __bf16 bf16;
typedef __bf16 bf16x2 __attribute__((ext_vector_type(2)));
typedef __bf16 bf16x4 __attribute__((ext_vector_type(4)));
typedef __bf16 bf16x8 __attribute__((ext_vector_type(8)));
typedef float  f32x4  __attribute__((ext_vector_type(4)));

// softmax scale folded with log2(e): attn uses exp2 instead of exp
constexpr float QSCALE = 0.125f * 1.44269504088896340736f;

// async global->LDS, 16B per lane. Dest = wave-uniform base + lane*16 (m104).
__device__ __forceinline__ void gll16(const void* g, void* l) {
    __builtin_amdgcn_global_load_lds((const __attribute__((address_space(1))) unsigned int*)g,
                                     (__attribute__((address_space(3))) unsigned int*)l, 16, 0, 0);
}

// gfx9 waitcnt: vmcnt[5:4]@[15:14] vmcnt[3:0]@[3:0] expcnt@[6:4] lgkmcnt@[11:8]
#define WAIT_VM0()   __builtin_amdgcn_s_waitcnt(0x0F70)   // vmcnt(0)
#define WAIT_VM8()   __builtin_amdgcn_s_waitcnt(0x0F78)   // vmcnt(8): prev tile landed, next in flight
#define WAIT_LGKM0() __builtin_amdgcn_s_waitcnt(0xC07F)   // lgkmcnt(0)

// ---------------------------------------------------------------------------
// Kernel 1: transpose + cast weights: w_{q,k,v}[1024][64] fp32 -> wT[3][64][1024] bf16
// ---------------------------------------------------------------------------
__global__ void prep_wT(const float* __restrict__ wq, const float* __restrict__ wk,
                        const float* __restrict__ wv, bf16* __restrict__ wT) {
    int idx = blockIdx.x * blockDim.x + threadIdx.x;
    if (idx >= 3 * TH * TC) return;
    int wsel = idx / (TH * TC);
    int rem  = idx % (TH * TC);
    int c = rem / TH;
    int h = rem % TH;
    const float* w = (wsel == 0) ? wq : (wsel == 1) ? wk : wv;
    wT[(size_t)wsel * TH * TC + (size_t)h * TC + c] = (bf16)w[(size_t)c * TH + h];
}

// ---------------------------------------------------------------------------
// Kernel 2: QKV projection v3 (verified R3). 256 blocks x 512 threads.
// R6: launched 3x as a decomposition probe (idempotent: reads x/wT, writes
// Q/K/VT). proj_time = (dur_us - 126.7)/2.
// ---------------------------------------------------------------------------
__launch_bounds__(512)
__global__ void proj(const float* __restrict__ x, const bf16* __restrict__ wT,
                     bf16* __restrict__ Q, bf16* __restrict__ K, bf16* __restrict__ VT) {
    __shared__ __align__(16) char lds[81920];   // X[2][16KB] @0, W[2][24KB] @32768
    const int tid  = threadIdx.x;
    const int wv8  = tid >> 6;                  // 0..7
    const int lane = tid & 63;
    const int quad = lane >> 4, l16 = lane & 15;
    const int rg   = wv8 & 3;                   // row group: 16 rows
    const int ch   = wv8 >> 2;                  // col half: 6 of 12 col-groups
    const int m0   = blockIdx.x * 64;

    const float* xb = x + (size_t)m0 * TC;

    f32x4 acc[6];
#pragma unroll
    for (int g = 0; g < 6; g++) acc[g] = f32x4{0.f, 0.f, 0.f, 0.f};

    const int lr16 = lane >> 4, lc16 = lane & 15;
    const int lr8  = lane >> 3, lc8  = lane & 7;

#define STAGE(kc, bb)                                                          \
    {                                                                          \
        _Pragma("unroll")                                                      \
        for (int i = 0; i < 2; i++) {          /* 16 X chunks over 8 waves */  \
            int base_row = wv8 * 8 + i * 4;                                    \
            int row = base_row + lr16;                                         \
            int c = lc16 ^ (row & 15);                                         \
            gll16(xb + (size_t)row * TC + (kc) * 64 + c * 4,                   \
                  lds + (bb) * 16384 + base_row * 256);                        \
        }                                                                      \
        _Pragma("unroll")                                                      \
        for (int j = 0; j < 3; j++) {          /* 24 W chunks over 8 waves */  \
            int idx = wv8 * 3 + j;                                             \
            int w = idx >> 3;                                                  \
            int base_col = (idx & 7) * 8;                                      \
            int col = base_col + lr8;                                          \
            int c = lc8 ^ (col & 7);                                           \
            gll16(wT + (size_t)w * TH * TC + (size_t)col * TC + (kc) * 64 + c * 8, \
                  lds + 32768 + (bb) * 24576 + (w * 64 + base_col) * 128);     \
        }                                                                      \
    }

    STAGE(0, 0);
    for (int kc = 0; kc < 16; kc++) {
        const int cur = kc & 1;
        __syncthreads();
        if (kc + 1 < 16) STAGE(kc + 1, cur ^ 1);
        const char* Xb = lds + cur * 16384;
        const char* Wb = lds + 32768 + cur * 24576;
        const int row = rg * 16 + l16;          // row&15 == l16: matches X swizzle
#pragma unroll
        for (int s = 0; s < 2; s++) {
            int c1 = (s * 8 + 2 * quad) ^ l16;
            int c2 = (s * 8 + 2 * quad + 1) ^ l16;
            f32x4 a0 = *(const f32x4*)(Xb + row * 256 + c1 * 16);
            f32x4 a1 = *(const f32x4*)(Xb + row * 256 + c2 * 16);
            bf16x8 af;
            af[0] = (bf16)a0[0]; af[1] = (bf16)a0[1]; af[2] = (bf16)a0[2]; af[3] = (bf16)a0[3];
            af[4] = (bf16)a1[0]; af[5] = (bf16)a1[1]; af[6] = (bf16)a1[2]; af[7] = (bf16)a1[3];
#pragma unroll
            for (int g = 0; g < 6; g++) {
                int cg = ch * 6 + g;            // 0..11 global col-group
                int w = cg >> 2;
                int col = (cg & 3) * 16 + l16;
                int c = (s * 4 + quad) ^ (col & 7);
                bf16x8 bq = *(const bf16x8*)(Wb + (w * 64 + col) * 128 + c * 16);
                acc[g] = __builtin_amdgcn_mfma_f32_16x16x32_bf16(af, bq, acc[g], 0, 0, 0);
            }
        }
    }

    // epilogue: C layout row = quad*4+r, col = (cg&3)*16+l16; w = cg>>2
    const int mrow = m0 + rg * 16 + quad * 4;
    const int b = m0 >> 11;            // 64-row tiles never cross batch boundary
    const int t = mrow & 2047;
#pragma unroll
    for (int g = 0; g < 6; g++) {
        int cg = ch * 6 + g;
        int w = cg >> 2;
        int col = (cg & 3) * 16 + l16;
        if (w == 0) {
#pragma unroll
            for (int r = 0; r < 4; r++)
                Q[(size_t)(mrow + r) * TH + col] = (bf16)(acc[g][r] * QSCALE);
        } else if (w == 1) {
#pragma unroll
            for (int r = 0; r < 4; r++)
                K[(size_t)(mrow + r) * TH + col] = (bf16)acc[g][r];
        } else {
            bf16x4 o;
#pragma unroll
            for (int r = 0; r < 4; r++) o[r] = (bf16)acc[g][r];
            *(bf16x4*)(VT + ((size_t)b * TH + col) * TT + t) = o;
        }
    }
}
#undef STAGE

// ---------------------------------------------------------------------------
// Kernel 3: causal flash attention v7 (verified R5 best, 126.66us) — fold-
// paired, XCD-aligned, one dispatch round. 256 blocks x 512 thr; waves 0-3
// run qc=j, waves 4-7 run qc=63-j; inner machinery = verified v5.
// (v8's no-LDS direct-load variant REGRESSED +8.5us — reverted.)
// ---------------------------------------------------------------------------
__device__ __forceinline__ float packbf(float a, float b) {
    union { bf16x2 h; float f; } u;
    u.h[0] = (bf16)a; u.h[1] = (bf16)b;
    return u.f;
}

__launch_bounds__(512, 2)
__global__ void attn(const bf16* __restrict__ Q, const bf16* __restrict__ K,
                     const bf16* __restrict__ VT, float* __restrict__ out) {
    // 8 waves x 16KB staging (K0,K1,V0,V1 4KB each); merge region reused after
    __shared__ __align__(16) char lds[131072];

    const int tid  = threadIdx.x;
    const int wv   = tid >> 6;                  // 0..7
    const int wvl  = wv & 3;                    // lane within chunk-group
    const int grp  = wv >> 2;                   // 0: chunk A (qc=j), 1: chunk B (qc=63-j)
    const int lane = tid & 63;
    const int quad = lane >> 4, l16 = lane & 15;
    const int b  = blockIdx.x & 7;              // head -> XCD b (round-robin, 1 round)
    const int j  = blockIdx.x >> 3;             // 0..31
    const int qc = grp ? (63 - j) : j;          // this wave-group's q-chunk
    const int q0 = qc * 32;

    char* Kst = lds + wv * 16384;
    char* Vst = Kst + 8192;

    const bf16* Qb = Q  + (size_t)b * TT * TH;
    const bf16* Kb = K  + (size_t)b * TT * TH;
    const bf16* Vb = VT + (size_t)b * TH * TT;

    // Q fragments (B-operand): B[k=h][n=q], q = q0 + qg*16 + l16
    bf16x8 bq[2][2];
#pragma unroll
    for (int qg = 0; qg < 2; qg++)
#pragma unroll
        for (int kh = 0; kh < 2; kh++)
            bq[qg][kh] = *(const bf16x8*)(Qb + (size_t)(q0 + qg * 16 + l16) * TH + kh * 32 + quad * 8);

    f32x4 accO[2][4];
#pragma unroll
    for (int qg = 0; qg < 2; qg++)
#pragma unroll
        for (int g = 0; g < 4; g++) accO[qg][g] = f32x4{0.f, 0.f, 0.f, 0.f};
    float lIp[2] = {0.f, 0.f};                  // per-lane partial row-sum (q = qg*16+l16)

    const int r8 = lane >> 3, c8 = lane & 7;    // K staging: 8 rows/instr
    const int r4 = lane >> 2, c4 = lane & 3;    // V staging: 16 rows/instr
    const int src1 = (quad & 1) * 32 + l16;     // bpermute source lanes
    const int src2 = src1 + 16;

    // stage 32-t tile kt_ into buffer bb_ (8 gll16: 4 K + 4 V)
#define STAGEKV(kt_, bb_)                                                       \
    {                                                                           \
        const int k0_ = (kt_) * 32;                                             \
        _Pragma("unroll")                                                       \
        for (int i = 0; i < 4; i++) {                                           \
            int t = i * 8 + r8;                                                 \
            gll16(Kb + (size_t)(k0_ + t) * 64 + ((c8 ^ r8) * 8),                \
                  Kst + (bb_) * 4096 + i * 1024);                               \
        }                                                                       \
        _Pragma("unroll")                                                       \
        for (int i = 0; i < 4; i++) {                                           \
            int h = i * 16 + r4;                                                \
            gll16(Vb + (size_t)h * TT + k0_ + ((c4 ^ quad) * 8),                \
                  Vst + (bb_) * 4096 + i * 1024);                               \
        }                                                                       \
    }

    if (wvl <= qc) {
        const int kt1 = (wvl + 4 <= qc) ? wvl + 4 : qc;   // clamped (keeps 8-DMA invariant)
        STAGEKV(wvl, 0);
        STAGEKV(kt1, 1);
        int nit = 0;
        for (int kt = wvl; kt <= qc; kt += 4, nit++) {
            const int bb = nit & 1;
            WAIT_VM8();                          // current tile landed; next stays in flight

            bf16x8 ka[2][2], bv[4];
#pragma unroll
            for (int g = 0; g < 2; g++) {
                int t = g * 16 + l16;
                const char* kr = Kst + bb * 4096 + t * 128;
                ka[g][0] = *(const bf16x8*)(kr + (((quad) ^ (t & 7)) << 4));
                ka[g][1] = *(const bf16x8*)(kr + (((4 + quad) ^ (t & 7)) << 4));
            }
#pragma unroll
            for (int g = 0; g < 4; g++) {
                int h = g * 16 + l16;
                bv[g] = *(const bf16x8*)(Vst + bb * 4096 + h * 64 + ((quad ^ (l16 >> 2)) << 4));
            }
            WAIT_LGKM0();                        // frags in regs; buffer reusable
            {
                int ktn = kt + 8; if (ktn > qc) ktn = qc;   // clamp, never skip
                STAGEKV(ktn, bb);
            }

            // St = K Q^T : s[qg][g] C-layout (t = g*16+quad*4+r, q = qg*16+l16)
            f32x4 s[2][2];
#pragma unroll
            for (int g = 0; g < 2; g++)
#pragma unroll
                for (int qg = 0; qg < 2; qg++) {
                    f32x4 t0 = f32x4{0.f, 0.f, 0.f, 0.f};
                    t0 = __builtin_amdgcn_mfma_f32_16x16x32_bf16(ka[g][0], bq[qg][0], t0, 0, 0, 0);
                    t0 = __builtin_amdgcn_mfma_f32_16x16x32_bf16(ka[g][1], bq[qg][1], t0, 0, 0, 0);
                    s[qg][g] = t0;
                }

            if (kt == qc) {                      // causal mask on diagonal tile
#pragma unroll
                for (int qg = 0; qg < 2; qg++) {
                    const int ql = qg * 16 + l16;
#pragma unroll
                    for (int g = 0; g < 2; g++)
#pragma unroll
                        for (int r = 0; r < 4; r++)
                            if (g * 16 + quad * 4 + r > ql) s[qg][g][r] = -3.0e38f;
                }
            }

            // p = exp2(s) directly (no max-sub; see header proof), accumulate
            // per-lane partial row-sums only — no cross-lane ops in the loop.
#pragma unroll
            for (int qg = 0; qg < 2; qg++) {
                float rs = 0.f;
#pragma unroll
                for (int g = 0; g < 2; g++)
#pragma unroll
                    for (int r = 0; r < 4; r++) {
                        float p = __builtin_amdgcn_exp2f(s[qg][g][r]);
                        s[qg][g][r] = p;
                        rs += p;
                    }
                lIp[qg] += rs;
            }

            // P: C->A transform via bpermute (t = quad*8+j; g = quad>>1)
#pragma unroll
            for (int qg = 0; qg < 2; qg++) {
                float p00 = packbf(s[qg][0][0], s[qg][0][1]);
                float p01 = packbf(s[qg][0][2], s[qg][0][3]);
                float p10 = packbf(s[qg][1][0], s[qg][1][1]);
                float p11 = packbf(s[qg][1][2], s[qg][1][3]);
                float A0p0 = __shfl(p00, src1), A0p1 = __shfl(p01, src1);
                float B0p0 = __shfl(p00, src2), B0p1 = __shfl(p01, src2);
                float A1p0 = __shfl(p10, src1), A1p1 = __shfl(p11, src1);
                float B1p0 = __shfl(p10, src2), B1p1 = __shfl(p11, src2);
                bool lo = quad < 2;
                union { float4 f; bf16x8 v; } u;
                u.f = make_float4(lo ? A0p0 : A1p0, lo ? A0p1 : A1p1,
                                  lo ? B0p0 : B1p0, lo ? B0p1 : B1p1);
#pragma unroll
                for (int g = 0; g < 4; g++)
                    accO[qg][g] = __builtin_amdgcn_mfma_f32_16x16x32_bf16(u.v, bv[g], accO[qg][g], 0, 0, 0);
            }
        }
    }
#undef STAGEKV

    // one-time row-sum reduction across the quad axis (t was split over quads)
    float lI[2];
#pragma unroll
    for (int qg = 0; qg < 2; qg++) {
        float l = lIp[qg];
        l += __shfl_xor(l, 16);
        l += __shfl_xor(l, 32);
        lI[qg] = l;
    }

    // ---- merge: per chunk-group, 4 waves' partial (O, l) in LDS ----
    // layout: Omg[2][4][32][68] f32 @0 (2x34816B), Lmg[2][4][32] @69632
    WAIT_VM0();                                  // dangling prefetch DMA drained
    __syncthreads();
    float* Omg = (float*)(lds + grp * 34816);
    float* Lmg = (float*)(lds + 69632 + grp * 512);
#pragma unroll
    for (int qg = 0; qg < 2; qg++)
#pragma unroll
        for (int g = 0; g < 4; g++)
#pragma unroll
            for (int r = 0; r < 4; r++)
                Omg[(size_t)(wvl * 32 + qg * 16 + quad * 4 + r) * 68 + g * 16 + l16] = accO[qg][g][r];
    if (quad == 0) {
#pragma unroll
        for (int qg = 0; qg < 2; qg++)
            Lmg[wvl * 32 + qg * 16 + l16] = lI[qg];
    }
    __syncthreads();

    // 1024 items = 2 chunks x 32 q x 16 h-groups; 512 threads, 2 passes
#pragma unroll
    for (int p = 0; p < 2; p++) {
        const int idx = p * 512 + tid;
        const int c  = idx >> 9;                // chunk 0 (qc=j) / 1 (qc=63-j)
        const int wi = idx & 511;
        const int q  = wi >> 4;
        const int hs = (wi & 15) * 4;
        const float* Om = (const float*)(lds + c * 34816);
        const float* Lm = (const float*)(lds + 69632 + c * 512);
        float denom = 0.f, o0 = 0.f, o1 = 0.f, o2 = 0.f, o3 = 0.f;
#pragma unroll
        for (int w = 0; w < 4; w++) {
            denom += Lm[w * 32 + q];
            const float* op = Om + (size_t)(w * 32 + q) * 68 + hs;
            o0 += op[0]; o1 += op[1]; o2 += op[2]; o3 += op[3];
        }
        float inv = 1.f / denom;
        const int q0c = (c ? (63 - j) : j) * 32;
        *(float4*)(out + ((size_t)b * TT + q0c + q) * TH + hs) =
            make_float4(o0 * inv, o1 * inv, o2 * inv, o3 * inv);
    }
}

// ---------------------------------------------------------------------------
// R6 DECOMPOSITION PROBE: proj launched 3x (idempotent — reads x/wT, writes
// Q/K/VT, no aliasing). proj_time = (dur_us − 126.7)/2. attn reverted to
// verified v7. Remove extra launches next round.
// ---------------------------------------------------------------------------
extern "C" void kernel_launch(void* const* d_in, const int* in_sizes, int n_in,
                              void* d_out, int out_size, void* d_ws, size_t ws_size,
                              hipStream_t stream) {
    const float* x  = (const float*)d_in[0];
    const float* wq = (const float*)d_in[1];
    const float* wk = (const float*)d_in[2];
    const float* wv = (const float*)d_in[3];

    char* ws = (char*)d_ws;
    bf16*  wT = (bf16*)(ws);                        // 393,216 B
    bf16*  Q  = (bf16*)(ws + 393216);               // 2 MB
    bf16*  K  = (bf16*)(ws + 2490368);              // 2 MB
    bf16*  VT = (bf16*)(ws + 4587520);              // 2 MB
    float* out = (float*)d_out;

    hipLaunchKernelGGL(prep_wT, dim3(768), dim3(256), 0, stream, wq, wk, wv, wT);
    hipLaunchKernelGGL(proj, dim3(256), dim3(512), 0, stream, x, wT, Q, K, VT);
    hipLaunchKernelGGL(proj, dim3(256), dim3(512), 0, stream, x, wT, Q, K, VT);
    hipLaunchKernelGGL(proj, dim3(256), dim3(512), 0, stream, x, wT, Q, K, VT);
    hipLaunchKernelGGL(attn, dim3(TB * 32), dim3(512), 0, stream, Q, K, VT, out);
}

// Round 8
// 125.362 us; speedup vs baseline: 1.3017x; 1.3017x over previous
//
#include <hip/hip_runtime.h>
#include <hip/hip_bf16.h>
#include <cstdint>

#define TB 8
#define TT 2048
#define TC 1024
#define TH 64

typedef __bf16 bf16;
typedef __bf16 bf16x2 __attribute__((ext_vector_type(2)));
typedef __bf16 bf16x4 __attribute__((ext_vector_type(4)));
typedef __bf16 bf16x8 __attribute__((ext_vector_type(8)));
typedef float  f32x4  __attribute__((ext_vector_type(4)));

// softmax scale folded with log2(e): attn uses exp2 instead of exp
constexpr float QSCALE = 0.125f * 1.44269504088896340736f;

// async global->LDS, 16B per lane. Dest = wave-uniform base + lane*16 (m104).
__device__ __forceinline__ void gll16(const void* g, void* l) {
    __builtin_amdgcn_global_load_lds((const __attribute__((address_space(1))) unsigned int*)g,
                                     (__attribute__((address_space(3))) unsigned int*)l, 16, 0, 0);
}

// gfx9 waitcnt: vmcnt[5:4]@[15:14] vmcnt[3:0]@[3:0] expcnt@[6:4] lgkmcnt@[11:8]
#define WAIT_VM0()   __builtin_amdgcn_s_waitcnt(0x0F70)   // vmcnt(0)
#define WAIT_VM5()   __builtin_amdgcn_s_waitcnt(0x0F75)   // vmcnt(5): 1 stage (5 DMA) may remain in flight
#define WAIT_VM8()   __builtin_amdgcn_s_waitcnt(0x0F78)   // vmcnt(8): prev tile landed, next in flight
#define WAIT_LGKM0() __builtin_amdgcn_s_waitcnt(0xC07F)   // lgkmcnt(0)

// ---------------------------------------------------------------------------
// Kernel 1: transpose + cast weights: w_{q,k,v}[1024][64] fp32 -> wT[3][64][1024] bf16
// ---------------------------------------------------------------------------
__global__ void prep_wT(const float* __restrict__ wq, const float* __restrict__ wk,
                        const float* __restrict__ wv, bf16* __restrict__ wT) {
    int idx = blockIdx.x * blockDim.x + threadIdx.x;
    if (idx >= 3 * TH * TC) return;
    int wsel = idx / (TH * TC);
    int rem  = idx % (TH * TC);
    int c = rem / TH;
    int h = rem % TH;
    const float* w = (wsel == 0) ? wq : (wsel == 1) ? wk : wv;
    wT[(size_t)wsel * TH * TC + (size_t)h * TC + c] = (bf16)w[(size_t)c * TH + h];
}

// ---------------------------------------------------------------------------
// Kernel 2: QKV projection v4 — counted-vmcnt pipeline (R7 probe: proj =
// 18.26us vs ~11us HBM floor; cause = __syncthreads' implicit vmcnt(0)
// drain serializing DMA to 1-tile depth; the m97 barrier-drain structure).
// v4: 3 LDS buffers (3 x [X 16KB | W 24KB] = 120KB), raw s_barrier (no
// drain) + per-wave counted WAIT_VM5 (each stage = exactly 5 gll16/wave:
// 2 X + 3 W). Loop: wait vm(5) [tile k landed, k+1 in flight] -> s_barrier
// [all waves' k landed] -> sched_barrier [no hoist] -> STAGE(k+2) ->
// compute(k). WAR-safe: stage(k+3) hits buf[k%3] only after the k+1
// barrier, by which time compute(k)'s ds_reads retired (lgkm-ordered).
// Same swizzles/compute/epilogue as verified v3.
// ---------------------------------------------------------------------------
__launch_bounds__(512)
__global__ void proj(const float* __restrict__ x, const bf16* __restrict__ wT,
                     bf16* __restrict__ Q, bf16* __restrict__ K, bf16* __restrict__ VT) {
    __shared__ __align__(16) char lds[122880];  // 3 x 40960: X @ b*40960, W @ b*40960+16384
    const int tid  = threadIdx.x;
    const int wv8  = tid >> 6;                  // 0..7
    const int lane = tid & 63;
    const int quad = lane >> 4, l16 = lane & 15;
    const int rg   = wv8 & 3;                   // row group: 16 rows
    const int ch   = wv8 >> 2;                  // col half: 6 of 12 col-groups
    const int m0   = blockIdx.x * 64;

    const float* xb = x + (size_t)m0 * TC;

    f32x4 acc[6];
#pragma unroll
    for (int g = 0; g < 6; g++) acc[g] = f32x4{0.f, 0.f, 0.f, 0.f};

    const int lr16 = lane >> 4, lc16 = lane & 15;
    const int lr8  = lane >> 3, lc8  = lane & 7;

#define STAGE(kc, bb)                                                          \
    {                                                                          \
        _Pragma("unroll")                                                      \
        for (int i = 0; i < 2; i++) {          /* 16 X chunks over 8 waves */  \
            int base_row = wv8 * 8 + i * 4;                                    \
            int row = base_row + lr16;                                         \
            int c = lc16 ^ (row & 15);                                         \
            gll16(xb + (size_t)row * TC + (kc) * 64 + c * 4,                   \
                  lds + (bb) * 40960 + base_row * 256);                        \
        }                                                                      \
        _Pragma("unroll")                                                      \
        for (int j = 0; j < 3; j++) {          /* 24 W chunks over 8 waves */  \
            int idx = wv8 * 3 + j;                                             \
            int w = idx >> 3;                                                  \
            int base_col = (idx & 7) * 8;                                      \
            int col = base_col + lr8;                                          \
            int c = lc8 ^ (col & 7);                                           \
            gll16(wT + (size_t)w * TH * TC + (size_t)col * TC + (kc) * 64 + c * 8, \
                  lds + (bb) * 40960 + 16384 + (w * 64 + base_col) * 128);     \
        }                                                                      \
    }

    STAGE(0, 0);
    STAGE(1, 1);
    for (int kc = 0; kc < 16; kc++) {
        const int cur = kc % 3;
        if (kc < 15) WAIT_VM5(); else WAIT_VM0();     // own tile-kc DMAs landed
        __builtin_amdgcn_s_barrier();                 // raw: no compiler vmcnt(0) drain
        __builtin_amdgcn_sched_barrier(0);            // no ds_read hoist above barrier
        if (kc + 2 < 16) STAGE(kc + 2, (kc + 2) % 3);
        const char* Xb = lds + cur * 40960;
        const char* Wb = lds + cur * 40960 + 16384;
        const int row = rg * 16 + l16;          // row&15 == l16: matches X swizzle
#pragma unroll
        for (int s = 0; s < 2; s++) {
            int c1 = (s * 8 + 2 * quad) ^ l16;
            int c2 = (s * 8 + 2 * quad + 1) ^ l16;
            f32x4 a0 = *(const f32x4*)(Xb + row * 256 + c1 * 16);
            f32x4 a1 = *(const f32x4*)(Xb + row * 256 + c2 * 16);
            bf16x8 af;
            af[0] = (bf16)a0[0]; af[1] = (bf16)a0[1]; af[2] = (bf16)a0[2]; af[3] = (bf16)a0[3];
            af[4] = (bf16)a1[0]; af[5] = (bf16)a1[1]; af[6] = (bf16)a1[2]; af[7] = (bf16)a1[3];
#pragma unroll
            for (int g = 0; g < 6; g++) {
                int cg = ch * 6 + g;            // 0..11 global col-group
                int w = cg >> 2;
                int col = (cg & 3) * 16 + l16;
                int c = (s * 4 + quad) ^ (col & 7);
                bf16x8 bq = *(const bf16x8*)(Wb + (w * 64 + col) * 128 + c * 16);
                acc[g] = __builtin_amdgcn_mfma_f32_16x16x32_bf16(af, bq, acc[g], 0, 0, 0);
            }
        }
    }

    // epilogue: C layout row = quad*4+r, col = (cg&3)*16+l16; w = cg>>2
    const int mrow = m0 + rg * 16 + quad * 4;
    const int b = m0 >> 11;            // 64-row tiles never cross batch boundary
    const int t = mrow & 2047;
#pragma unroll
    for (int g = 0; g < 6; g++) {
        int cg = ch * 6 + g;
        int w = cg >> 2;
        int col = (cg & 3) * 16 + l16;
        if (w == 0) {
#pragma unroll
            for (int r = 0; r < 4; r++)
                Q[(size_t)(mrow + r) * TH + col] = (bf16)(acc[g][r] * QSCALE);
        } else if (w == 1) {
#pragma unroll
            for (int r = 0; r < 4; r++)
                K[(size_t)(mrow + r) * TH + col] = (bf16)acc[g][r];
        } else {
            bf16x4 o;
#pragma unroll
            for (int r = 0; r < 4; r++) o[r] = (bf16)acc[g][r];
            *(bf16x4*)(VT + ((size_t)b * TH + col) * TT + t) = o;
        }
    }
}
#undef STAGE

// ---------------------------------------------------------------------------
// Kernel 3: causal flash attention v7 (verified best, 126.66us) — fold-
// paired, XCD-aligned, one dispatch round. 256 blocks x 512 thr; waves 0-3
// run qc=j, waves 4-7 run qc=63-j; inner machinery = verified v5.
// ---------------------------------------------------------------------------
__device__ __forceinline__ float packbf(float a, float b) {
    union { bf16x2 h; float f; } u;
    u.h[0] = (bf16)a; u.h[1] = (bf16)b;
    return u.f;
}

__launch_bounds__(512, 2)
__global__ void attn(const bf16* __restrict__ Q, const bf16* __restrict__ K,
                     const bf16* __restrict__ VT, float* __restrict__ out) {
    // 8 waves x 16KB staging (K0,K1,V0,V1 4KB each); merge region reused after
    __shared__ __align__(16) char lds[131072];

    const int tid  = threadIdx.x;
    const int wv   = tid >> 6;                  // 0..7
    const int wvl  = wv & 3;                    // lane within chunk-group
    const int grp  = wv >> 2;                   // 0: chunk A (qc=j), 1: chunk B (qc=63-j)
    const int lane = tid & 63;
    const int quad = lane >> 4, l16 = lane & 15;
    const int b  = blockIdx.x & 7;              // head -> XCD b (round-robin, 1 round)
    const int j  = blockIdx.x >> 3;             // 0..31
    const int qc = grp ? (63 - j) : j;          // this wave-group's q-chunk
    const int q0 = qc * 32;

    char* Kst = lds + wv * 16384;
    char* Vst = Kst + 8192;

    const bf16* Qb = Q  + (size_t)b * TT * TH;
    const bf16* Kb = K  + (size_t)b * TT * TH;
    const bf16* Vb = VT + (size_t)b * TH * TT;

    // Q fragments (B-operand): B[k=h][n=q], q = q0 + qg*16 + l16
    bf16x8 bq[2][2];
#pragma unroll
    for (int qg = 0; qg < 2; qg++)
#pragma unroll
        for (int kh = 0; kh < 2; kh++)
            bq[qg][kh] = *(const bf16x8*)(Qb + (size_t)(q0 + qg * 16 + l16) * TH + kh * 32 + quad * 8);

    f32x4 accO[2][4];
#pragma unroll
    for (int qg = 0; qg < 2; qg++)
#pragma unroll
        for (int g = 0; g < 4; g++) accO[qg][g] = f32x4{0.f, 0.f, 0.f, 0.f};
    float lIp[2] = {0.f, 0.f};                  // per-lane partial row-sum (q = qg*16+l16)

    const int r8 = lane >> 3, c8 = lane & 7;    // K staging: 8 rows/instr
    const int r4 = lane >> 2, c4 = lane & 3;    // V staging: 16 rows/instr
    const int src1 = (quad & 1) * 32 + l16;     // bpermute source lanes
    const int src2 = src1 + 16;

    // stage 32-t tile kt_ into buffer bb_ (8 gll16: 4 K + 4 V)
#define STAGEKV(kt_, bb_)                                                       \
    {                                                                           \
        const int k0_ = (kt_) * 32;                                             \
        _Pragma("unroll")                                                       \
        for (int i = 0; i < 4; i++) {                                           \
            int t = i * 8 + r8;                                                 \
            gll16(Kb + (size_t)(k0_ + t) * 64 + ((c8 ^ r8) * 8),                \
                  Kst + (bb_) * 4096 + i * 1024);                               \
        }                                                                       \
        _Pragma("unroll")                                                       \
        for (int i = 0; i < 4; i++) {                                           \
            int h = i * 16 + r4;                                                \
            gll16(Vb + (size_t)h * TT + k0_ + ((c4 ^ quad) * 8),                \
                  Vst + (bb_) * 4096 + i * 1024);                               \
        }                                                                       \
    }

    if (wvl <= qc) {
        const int kt1 = (wvl + 4 <= qc) ? wvl + 4 : qc;   // clamped (keeps 8-DMA invariant)
        STAGEKV(wvl, 0);
        STAGEKV(kt1, 1);
        int nit = 0;
        for (int kt = wvl; kt <= qc; kt += 4, nit++) {
            const int bb = nit & 1;
            WAIT_VM8();                          // current tile landed; next stays in flight

            bf16x8 ka[2][2], bv[4];
#pragma unroll
            for (int g = 0; g < 2; g++) {
                int t = g * 16 + l16;
                const char* kr = Kst + bb * 4096 + t * 128;
                ka[g][0] = *(const bf16x8*)(kr + (((quad) ^ (t & 7)) << 4));
                ka[g][1] = *(const bf16x8*)(kr + (((4 + quad) ^ (t & 7)) << 4));
            }
#pragma unroll
            for (int g = 0; g < 4; g++) {
                int h = g * 16 + l16;
                bv[g] = *(const bf16x8*)(Vst + bb * 4096 + h * 64 + ((quad ^ (l16 >> 2)) << 4));
            }
            WAIT_LGKM0();                        // frags in regs; buffer reusable
            {
                int ktn = kt + 8; if (ktn > qc) ktn = qc;   // clamp, never skip
                STAGEKV(ktn, bb);
            }

            // St = K Q^T : s[qg][g] C-layout (t = g*16+quad*4+r, q = qg*16+l16)
            f32x4 s[2][2];
#pragma unroll
            for (int g = 0; g < 2; g++)
#pragma unroll
                for (int qg = 0; qg < 2; qg++) {
                    f32x4 t0 = f32x4{0.f, 0.f, 0.f, 0.f};
                    t0 = __builtin_amdgcn_mfma_f32_16x16x32_bf16(ka[g][0], bq[qg][0], t0, 0, 0, 0);
                    t0 = __builtin_amdgcn_mfma_f32_16x16x32_bf16(ka[g][1], bq[qg][1], t0, 0, 0, 0);
                    s[qg][g] = t0;
                }

            if (kt == qc) {                      // causal mask on diagonal tile
#pragma unroll
                for (int qg = 0; qg < 2; qg++) {
                    const int ql = qg * 16 + l16;
#pragma unroll
                    for (int g = 0; g < 2; g++)
#pragma unroll
                        for (int r = 0; r < 4; r++)
                            if (g * 16 + quad * 4 + r > ql) s[qg][g][r] = -3.0e38f;
                }
            }

            // p = exp2(s) directly (no max-sub; see header proof), accumulate
            // per-lane partial row-sums only — no cross-lane ops in the loop.
#pragma unroll
            for (int qg = 0; qg < 2; qg++) {
                float rs = 0.f;
#pragma unroll
                for (int g = 0; g < 2; g++)
#pragma unroll
                    for (int r = 0; r < 4; r++) {
                        float p = __builtin_amdgcn_exp2f(s[qg][g][r]);
                        s[qg][g][r] = p;
                        rs += p;
                    }
                lIp[qg] += rs;
            }

            // P: C->A transform via bpermute (t = quad*8+j; g = quad>>1)
#pragma unroll
            for (int qg = 0; qg < 2; qg++) {
                float p00 = packbf(s[qg][0][0], s[qg][0][1]);
                float p01 = packbf(s[qg][0][2], s[qg][0][3]);
                float p10 = packbf(s[qg][1][0], s[qg][1][1]);
                float p11 = packbf(s[qg][1][2], s[qg][1][3]);
                float A0p0 = __shfl(p00, src1), A0p1 = __shfl(p01, src1);
                float B0p0 = __shfl(p00, src2), B0p1 = __shfl(p01, src2);
                float A1p0 = __shfl(p10, src1), A1p1 = __shfl(p11, src1);
                float B1p0 = __shfl(p10, src2), B1p1 = __shfl(p11, src2);
                bool lo = quad < 2;
                union { float4 f; bf16x8 v; } u;
                u.f = make_float4(lo ? A0p0 : A1p0, lo ? A0p1 : A1p1,
                                  lo ? B0p0 : B1p0, lo ? B0p1 : B1p1);
#pragma unroll
                for (int g = 0; g < 4; g++)
                    accO[qg][g] = __builtin_amdgcn_mfma_f32_16x16x32_bf16(u.v, bv[g], accO[qg][g], 0, 0, 0);
            }
        }
    }
#undef STAGEKV

    // one-time row-sum reduction across the quad axis (t was split over quads)
    float lI[2];
#pragma unroll
    for (int qg = 0; qg < 2; qg++) {
        float l = lIp[qg];
        l += __shfl_xor(l, 16);
        l += __shfl_xor(l, 32);
        lI[qg] = l;
    }

    // ---- merge: per chunk-group, 4 waves' partial (O, l) in LDS ----
    // layout: Omg[2][4][32][68] f32 @0 (2x34816B), Lmg[2][4][32] @69632
    WAIT_VM0();                                  // dangling prefetch DMA drained
    __syncthreads();
    float* Omg = (float*)(lds + grp * 34816);
    float* Lmg = (float*)(lds + 69632 + grp * 512);
#pragma unroll
    for (int qg = 0; qg < 2; qg++)
#pragma unroll
        for (int g = 0; g < 4; g++)
#pragma unroll
            for (int r = 0; r < 4; r++)
                Omg[(size_t)(wvl * 32 + qg * 16 + quad * 4 + r) * 68 + g * 16 + l16] = accO[qg][g][r];
    if (quad == 0) {
#pragma unroll
        for (int qg = 0; qg < 2; qg++)
            Lmg[wvl * 32 + qg * 16 + l16] = lI[qg];
    }
    __syncthreads();

    // 1024 items = 2 chunks x 32 q x 16 h-groups; 512 threads, 2 passes
#pragma unroll
    for (int p = 0; p < 2; p++) {
        const int idx = p * 512 + tid;
        const int c  = idx >> 9;                // chunk 0 (qc=j) / 1 (qc=63-j)
        const int wi = idx & 511;
        const int q  = wi >> 4;
        const int hs = (wi & 15) * 4;
        const float* Om = (const float*)(lds + c * 34816);
        const float* Lm = (const float*)(lds + 69632 + c * 512);
        float denom = 0.f, o0 = 0.f, o1 = 0.f, o2 = 0.f, o3 = 0.f;
#pragma unroll
        for (int w = 0; w < 4; w++) {
            denom += Lm[w * 32 + q];
            const float* op = Om + (size_t)(w * 32 + q) * 68 + hs;
            o0 += op[0]; o1 += op[1]; o2 += op[2]; o3 += op[3];
        }
        float inv = 1.f / denom;
        const int q0c = (c ? (63 - j) : j) * 32;
        *(float4*)(out + ((size_t)b * TT + q0c + q) * TH + hs) =
            make_float4(o0 * inv, o1 * inv, o2 * inv, o3 * inv);
    }
}

// ---------------------------------------------------------------------------
extern "C" void kernel_launch(void* const* d_in, const int* in_sizes, int n_in,
                              void* d_out, int out_size, void* d_ws, size_t ws_size,
                              hipStream_t stream) {
    const float* x  = (const float*)d_in[0];
    const float* wq = (const float*)d_in[1];
    const float* wk = (const float*)d_in[2];
    const float* wv = (const float*)d_in[3];

    char* ws = (char*)d_ws;
    bf16*  wT = (bf16*)(ws);                        // 393,216 B
    bf16*  Q  = (bf16*)(ws + 393216);               // 2 MB
    bf16*  K  = (bf16*)(ws + 2490368);              // 2 MB
    bf16*  VT = (bf16*)(ws + 4587520);              // 2 MB
    float* out = (float*)d_out;

    hipLaunchKernelGGL(prep_wT, dim3(768), dim3(256), 0, stream, wq, wk, wv, wT);
    hipLaunchKernelGGL(proj, dim3(256), dim3(512), 0, stream, x, wT, Q, K, VT);
    hipLaunchKernelGGL(attn, dim3(TB * 32), dim3(512), 0, stream, Q, K, VT, out);
}

// Round 9
// 124.968 us; speedup vs baseline: 1.3058x; 1.0032x over previous
//
#include <hip/hip_runtime.h>
#include <hip/hip_bf16.h>
#include <cstdint>

#define TB 8
#define TT 2048
#define TC 1024
#define TH 64

typedef __bf16 bf16;
typedef __bf16 bf16x2 __attribute__((ext_vector_type(2)));
typedef __bf16 bf16x4 __attribute__((ext_vector_type(4)));
typedef __bf16 bf16x8 __attribute__((ext_vector_type(8)));
typedef float  f32x4  __attribute__((ext_vector_type(4)));

// softmax scale folded with log2(e): attn uses exp2 instead of exp
constexpr float QSCALE = 0.125f * 1.44269504088896340736f;

// async global->LDS, 16B per lane. Dest = wave-uniform base + lane*16 (m104).
__device__ __forceinline__ void gll16(const void* g, void* l) {
    __builtin_amdgcn_global_load_lds((const __attribute__((address_space(1))) unsigned int*)g,
                                     (__attribute__((address_space(3))) unsigned int*)l, 16, 0, 0);
}

// gfx9 waitcnt: vmcnt[5:4]@[15:14] vmcnt[3:0]@[3:0] expcnt@[6:4] lgkmcnt@[11:8]
#define WAIT_VM0()   __builtin_amdgcn_s_waitcnt(0x0F70)   // vmcnt(0)
#define WAIT_VM5()   __builtin_amdgcn_s_waitcnt(0x0F75)   // vmcnt(5): 1 stage (5 DMA) may remain in flight
#define WAIT_VM8()   __builtin_amdgcn_s_waitcnt(0x0F78)   // vmcnt(8): prev tile landed, next in flight
#define WAIT_LGKM0() __builtin_amdgcn_s_waitcnt(0xC07F)   // lgkmcnt(0)

// ---------------------------------------------------------------------------
// Kernel 1: transpose + cast weights: w_{q,k,v}[1024][64] fp32 -> wT[3][64][1024] bf16
// ---------------------------------------------------------------------------
__global__ void prep_wT(const float* __restrict__ wq, const float* __restrict__ wk,
                        const float* __restrict__ wv, bf16* __restrict__ wT) {
    int idx = blockIdx.x * blockDim.x + threadIdx.x;
    if (idx >= 3 * TH * TC) return;
    int wsel = idx / (TH * TC);
    int rem  = idx % (TH * TC);
    int c = rem / TH;
    int h = rem % TH;
    const float* w = (wsel == 0) ? wq : (wsel == 1) ? wk : wv;
    wT[(size_t)wsel * TH * TC + (size_t)h * TC + c] = (bf16)w[(size_t)c * TH + h];
}

// ---------------------------------------------------------------------------
// Kernel 2: QKV projection v4 (verified R8, ~17us). Counted-vmcnt pipeline:
// 3 LDS buffers (120KB), raw s_barrier (no drain) + per-wave WAIT_VM5
// (each stage = exactly 5 gll16/wave: 2 X + 3 W). Same swizzles/compute/
// epilogue as verified v3.
// ---------------------------------------------------------------------------
__launch_bounds__(512)
__global__ void proj(const float* __restrict__ x, const bf16* __restrict__ wT,
                     bf16* __restrict__ Q, bf16* __restrict__ K, bf16* __restrict__ VT) {
    __shared__ __align__(16) char lds[122880];  // 3 x 40960: X @ b*40960, W @ b*40960+16384
    const int tid  = threadIdx.x;
    const int wv8  = tid >> 6;                  // 0..7
    const int lane = tid & 63;
    const int quad = lane >> 4, l16 = lane & 15;
    const int rg   = wv8 & 3;                   // row group: 16 rows
    const int ch   = wv8 >> 2;                  // col half: 6 of 12 col-groups
    const int m0   = blockIdx.x * 64;

    const float* xb = x + (size_t)m0 * TC;

    f32x4 acc[6];
#pragma unroll
    for (int g = 0; g < 6; g++) acc[g] = f32x4{0.f, 0.f, 0.f, 0.f};

    const int lr16 = lane >> 4, lc16 = lane & 15;
    const int lr8  = lane >> 3, lc8  = lane & 7;

#define STAGE(kc, bb)                                                          \
    {                                                                          \
        _Pragma("unroll")                                                      \
        for (int i = 0; i < 2; i++) {          /* 16 X chunks over 8 waves */  \
            int base_row = wv8 * 8 + i * 4;                                    \
            int row = base_row + lr16;                                         \
            int c = lc16 ^ (row & 15);                                         \
            gll16(xb + (size_t)row * TC + (kc) * 64 + c * 4,                   \
                  lds + (bb) * 40960 + base_row * 256);                        \
        }                                                                      \
        _Pragma("unroll")                                                      \
        for (int j = 0; j < 3; j++) {          /* 24 W chunks over 8 waves */  \
            int idx = wv8 * 3 + j;                                             \
            int w = idx >> 3;                                                  \
            int base_col = (idx & 7) * 8;                                      \
            int col = base_col + lr8;                                          \
            int c = lc8 ^ (col & 7);                                           \
            gll16(wT + (size_t)w * TH * TC + (size_t)col * TC + (kc) * 64 + c * 8, \
                  lds + (bb) * 40960 + 16384 + (w * 64 + base_col) * 128);     \
        }                                                                      \
    }

    STAGE(0, 0);
    STAGE(1, 1);
    for (int kc = 0; kc < 16; kc++) {
        const int cur = kc % 3;
        if (kc < 15) WAIT_VM5(); else WAIT_VM0();     // own tile-kc DMAs landed
        __builtin_amdgcn_s_barrier();                 // raw: no compiler vmcnt(0) drain
        __builtin_amdgcn_sched_barrier(0);            // no ds_read hoist above barrier
        if (kc + 2 < 16) STAGE(kc + 2, (kc + 2) % 3);
        const char* Xb = lds + cur * 40960;
        const char* Wb = lds + cur * 40960 + 16384;
        const int row = rg * 16 + l16;          // row&15 == l16: matches X swizzle
#pragma unroll
        for (int s = 0; s < 2; s++) {
            int c1 = (s * 8 + 2 * quad) ^ l16;
            int c2 = (s * 8 + 2 * quad + 1) ^ l16;
            f32x4 a0 = *(const f32x4*)(Xb + row * 256 + c1 * 16);
            f32x4 a1 = *(const f32x4*)(Xb + row * 256 + c2 * 16);
            bf16x8 af;
            af[0] = (bf16)a0[0]; af[1] = (bf16)a0[1]; af[2] = (bf16)a0[2]; af[3] = (bf16)a0[3];
            af[4] = (bf16)a1[0]; af[5] = (bf16)a1[1]; af[6] = (bf16)a1[2]; af[7] = (bf16)a1[3];
#pragma unroll
            for (int g = 0; g < 6; g++) {
                int cg = ch * 6 + g;            // 0..11 global col-group
                int w = cg >> 2;
                int col = (cg & 3) * 16 + l16;
                int c = (s * 4 + quad) ^ (col & 7);
                bf16x8 bq = *(const bf16x8*)(Wb + (w * 64 + col) * 128 + c * 16);
                acc[g] = __builtin_amdgcn_mfma_f32_16x16x32_bf16(af, bq, acc[g], 0, 0, 0);
            }
        }
    }

    // epilogue: C layout row = quad*4+r, col = (cg&3)*16+l16; w = cg>>2
    const int mrow = m0 + rg * 16 + quad * 4;
    const int b = m0 >> 11;            // 64-row tiles never cross batch boundary
    const int t = mrow & 2047;
#pragma unroll
    for (int g = 0; g < 6; g++) {
        int cg = ch * 6 + g;
        int w = cg >> 2;
        int col = (cg & 3) * 16 + l16;
        if (w == 0) {
#pragma unroll
            for (int r = 0; r < 4; r++)
                Q[(size_t)(mrow + r) * TH + col] = (bf16)(acc[g][r] * QSCALE);
        } else if (w == 1) {
#pragma unroll
            for (int r = 0; r < 4; r++)
                K[(size_t)(mrow + r) * TH + col] = (bf16)acc[g][r];
        } else {
            bf16x4 o;
#pragma unroll
            for (int r = 0; r < 4; r++) o[r] = (bf16)acc[g][r];
            *(bf16x4*)(VT + ((size_t)b * TH + col) * TT + t) = o;
        }
    }
}
#undef STAGE

// ---------------------------------------------------------------------------
// Kernel 3: causal flash attention v9 — cross-iteration software pipeline on
// the verified v7 structure. R8 model: per-iter serial chain ~1300 cyc
// (vmwait -> 16 ds_read(130 lat) -> QK -> exp2 -> pack -> 16 shfl(190+130)
// -> PV) vs ~450 cyc work; 2 waves/SIMD -> 646 cyc/iter measured. v9 splits
// tile work into {load+QK} and {SM+PV}: iter k issues ds_reads(k), runs
// SMPV(k-1) under the ds latency (exp2/pack = pure VALU; its shfls FIFO
// behind the ds_reads), then lgkm0 -> stage(k+2) -> QK(k). exp2/shfl/PV
// leave the QK->PV critical path. Peeled first tile + epilogue SMPV.
// All sub-transforms byte-identical to verified v7.
// ---------------------------------------------------------------------------
__device__ __forceinline__ float packbf(float a, float b) {
    union { bf16x2 h; float f; } u;
    u.h[0] = (bf16)a; u.h[1] = (bf16)b;
    return u.f;
}

__launch_bounds__(512, 2)
__global__ void attn(const bf16* __restrict__ Q, const bf16* __restrict__ K,
                     const bf16* __restrict__ VT, float* __restrict__ out) {
    // 8 waves x 16KB staging (K0,K1,V0,V1 4KB each); merge region reused after
    __shared__ __align__(16) char lds[131072];

    const int tid  = threadIdx.x;
    const int wv   = tid >> 6;                  // 0..7
    const int wvl  = wv & 3;                    // lane within chunk-group
    const int grp  = wv >> 2;                   // 0: chunk A (qc=j), 1: chunk B (qc=63-j)
    const int lane = tid & 63;
    const int quad = lane >> 4, l16 = lane & 15;
    const int b  = blockIdx.x & 7;              // head -> XCD b (round-robin, 1 round)
    const int j  = blockIdx.x >> 3;             // 0..31
    const int qc = grp ? (63 - j) : j;          // this wave-group's q-chunk
    const int q0 = qc * 32;

    char* Kst = lds + wv * 16384;
    char* Vst = Kst + 8192;

    const bf16* Qb = Q  + (size_t)b * TT * TH;
    const bf16* Kb = K  + (size_t)b * TT * TH;
    const bf16* Vb = VT + (size_t)b * TH * TT;

    // Q fragments (B-operand): B[k=h][n=q], q = q0 + qg*16 + l16
    bf16x8 bq[2][2];
#pragma unroll
    for (int qg = 0; qg < 2; qg++)
#pragma unroll
        for (int kh = 0; kh < 2; kh++)
            bq[qg][kh] = *(const bf16x8*)(Qb + (size_t)(q0 + qg * 16 + l16) * TH + kh * 32 + quad * 8);

    f32x4 accO[2][4];
#pragma unroll
    for (int qg = 0; qg < 2; qg++)
#pragma unroll
        for (int g = 0; g < 4; g++) accO[qg][g] = f32x4{0.f, 0.f, 0.f, 0.f};
    float lIp[2] = {0.f, 0.f};                  // per-lane partial row-sum (q = qg*16+l16)

    const int r8 = lane >> 3, c8 = lane & 7;    // K staging: 8 rows/instr
    const int r4 = lane >> 2, c4 = lane & 3;    // V staging: 16 rows/instr
    const int src1 = (quad & 1) * 32 + l16;     // bpermute source lanes
    const int src2 = src1 + 16;

    // stage 32-t tile kt_ into buffer bb_ (8 gll16: 4 K + 4 V)
#define STAGEKV(kt_, bb_)                                                       \
    {                                                                           \
        const int k0_ = (kt_) * 32;                                             \
        _Pragma("unroll")                                                       \
        for (int i = 0; i < 4; i++) {                                           \
            int t = i * 8 + r8;                                                 \
            gll16(Kb + (size_t)(k0_ + t) * 64 + ((c8 ^ r8) * 8),                \
                  Kst + (bb_) * 4096 + i * 1024);                               \
        }                                                                       \
        _Pragma("unroll")                                                       \
        for (int i = 0; i < 4; i++) {                                           \
            int h = i * 16 + r4;                                                \
            gll16(Vb + (size_t)h * TT + k0_ + ((c4 ^ quad) * 8),                \
                  Vst + (bb_) * 4096 + i * 1024);                               \
        }                                                                       \
    }

    // LDS -> reg MFMA fragments from buffer bb_ (identical to verified reads)
#define LOADFRAG(KA, BV, bb_)                                                   \
    {                                                                           \
        _Pragma("unroll")                                                       \
        for (int g = 0; g < 2; g++) {                                           \
            int t = g * 16 + l16;                                               \
            const char* kr = Kst + (bb_) * 4096 + t * 128;                      \
            KA[g][0] = *(const bf16x8*)(kr + (((quad) ^ (t & 7)) << 4));        \
            KA[g][1] = *(const bf16x8*)(kr + (((4 + quad) ^ (t & 7)) << 4));    \
        }                                                                       \
        _Pragma("unroll")                                                       \
        for (int g = 0; g < 4; g++) {                                           \
            int h = g * 16 + l16;                                               \
            BV[g] = *(const bf16x8*)(Vst + (bb_) * 4096 + h * 64 + ((quad ^ (l16 >> 2)) << 4)); \
        }                                                                       \
    }

    // St = K Q^T : S[qg][g] C-layout (t = g*16+quad*4+r, q = qg*16+l16)
#define QKT(KA, S)                                                              \
    _Pragma("unroll")                                                           \
    for (int g = 0; g < 2; g++)                                                 \
        _Pragma("unroll")                                                       \
        for (int qg = 0; qg < 2; qg++) {                                        \
            f32x4 t0 = f32x4{0.f, 0.f, 0.f, 0.f};                               \
            t0 = __builtin_amdgcn_mfma_f32_16x16x32_bf16(KA[g][0], bq[qg][0], t0, 0, 0, 0); \
            t0 = __builtin_amdgcn_mfma_f32_16x16x32_bf16(KA[g][1], bq[qg][1], t0, 0, 0, 0); \
            S[qg][g] = t0;                                                      \
        }

#define MASKDIAG(S)                                                             \
    _Pragma("unroll")                                                           \
    for (int qg = 0; qg < 2; qg++) {                                            \
        const int ql = qg * 16 + l16;                                           \
        _Pragma("unroll")                                                       \
        for (int g = 0; g < 2; g++)                                             \
            _Pragma("unroll")                                                   \
            for (int r = 0; r < 4; r++)                                         \
                if (g * 16 + quad * 4 + r > ql) S[qg][g][r] = -3.0e38f;         \
    }

    // softmax finish + PV for a tile whose scores are in S, V-frags in BV
#define SMPV(S, BV)                                                             \
    {                                                                           \
        _Pragma("unroll")                                                       \
        for (int qg = 0; qg < 2; qg++) {                                        \
            float rs = 0.f;                                                     \
            _Pragma("unroll")                                                   \
            for (int g = 0; g < 2; g++)                                         \
                _Pragma("unroll")                                               \
                for (int r = 0; r < 4; r++) {                                   \
                    float p = __builtin_amdgcn_exp2f(S[qg][g][r]);              \
                    S[qg][g][r] = p;                                            \
                    rs += p;                                                    \
                }                                                               \
            lIp[qg] += rs;                                                      \
        }                                                                       \
        _Pragma("unroll")                                                       \
        for (int qg = 0; qg < 2; qg++) {                                        \
            float p00 = packbf(S[qg][0][0], S[qg][0][1]);                       \
            float p01 = packbf(S[qg][0][2], S[qg][0][3]);                       \
            float p10 = packbf(S[qg][1][0], S[qg][1][1]);                       \
            float p11 = packbf(S[qg][1][2], S[qg][1][3]);                       \
            float A0p0 = __shfl(p00, src1), A0p1 = __shfl(p01, src1);           \
            float B0p0 = __shfl(p00, src2), B0p1 = __shfl(p01, src2);           \
            float A1p0 = __shfl(p10, src1), A1p1 = __shfl(p11, src1);           \
            float B1p0 = __shfl(p10, src2), B1p1 = __shfl(p11, src2);           \
            bool lo = quad < 2;                                                 \
            union { float4 f; bf16x8 v; } u;                                    \
            u.f = make_float4(lo ? A0p0 : A1p0, lo ? A0p1 : A1p1,               \
                              lo ? B0p0 : B1p0, lo ? B0p1 : B1p1);              \
            _Pragma("unroll")                                                   \
            for (int g = 0; g < 4; g++)                                         \
                accO[qg][g] = __builtin_amdgcn_mfma_f32_16x16x32_bf16(u.v, BV[g], accO[qg][g], 0, 0, 0); \
        }                                                                       \
    }

    if (wvl <= qc) {
        const int kt1 = (wvl + 4 <= qc) ? wvl + 4 : qc;   // clamped (keeps 8-DMA invariant)
        STAGEKV(wvl, 0);
        STAGEKV(kt1, 1);

        f32x4  sP[2][2];
        bf16x8 bvP[4];

        // ---- peel: tile wvl (buf 0): load + QK only ----
        {
            WAIT_VM8();                          // buf0 landed; buf1 in flight
            bf16x8 ka[2][2];
            LOADFRAG(ka, bvP, 0);
            WAIT_LGKM0();
            __builtin_amdgcn_sched_barrier(0);
            { int ktn = wvl + 8; if (ktn > qc) ktn = qc; STAGEKV(ktn, 0); }
            QKT(ka, sP);
            if (wvl == qc) MASKDIAG(sP);
        }

        int nit = 1;
        for (int kt = wvl + 4; kt <= qc; kt += 4, nit++) {
            const int bb = nit & 1;
            WAIT_VM8();                          // tile kt landed; next in flight
            bf16x8 ka[2][2], bvC[4];
            LOADFRAG(ka, bvC, bb);               // issue ds_reads early
            SMPV(sP, bvP);                       // finish tile kt-4 under ds latency
            WAIT_LGKM0();                        // frags in regs; buffer reusable
            __builtin_amdgcn_sched_barrier(0);
            { int ktn = kt + 8; if (ktn > qc) ktn = qc; STAGEKV(ktn, bb); }
            QKT(ka, sP);
            if (kt == qc) MASKDIAG(sP);
#pragma unroll
            for (int g = 0; g < 4; g++) bvP[g] = bvC[g];
        }

        SMPV(sP, bvP);                           // epilogue: finish last tile
    }
#undef STAGEKV
#undef LOADFRAG
#undef QKT
#undef MASKDIAG
#undef SMPV

    // one-time row-sum reduction across the quad axis (t was split over quads)
    float lI[2];
#pragma unroll
    for (int qg = 0; qg < 2; qg++) {
        float l = lIp[qg];
        l += __shfl_xor(l, 16);
        l += __shfl_xor(l, 32);
        lI[qg] = l;
    }

    // ---- merge: per chunk-group, 4 waves' partial (O, l) in LDS ----
    // layout: Omg[2][4][32][68] f32 @0 (2x34816B), Lmg[2][4][32] @69632
    WAIT_VM0();                                  // dangling prefetch DMA drained
    __syncthreads();
    float* Omg = (float*)(lds + grp * 34816);
    float* Lmg = (float*)(lds + 69632 + grp * 512);
#pragma unroll
    for (int qg = 0; qg < 2; qg++)
#pragma unroll
        for (int g = 0; g < 4; g++)
#pragma unroll
            for (int r = 0; r < 4; r++)
                Omg[(size_t)(wvl * 32 + qg * 16 + quad * 4 + r) * 68 + g * 16 + l16] = accO[qg][g][r];
    if (quad == 0) {
#pragma unroll
        for (int qg = 0; qg < 2; qg++)
            Lmg[wvl * 32 + qg * 16 + l16] = lI[qg];
    }
    __syncthreads();

    // 1024 items = 2 chunks x 32 q x 16 h-groups; 512 threads, 2 passes
#pragma unroll
    for (int p = 0; p < 2; p++) {
        const int idx = p * 512 + tid;
        const int c  = idx >> 9;                // chunk 0 (qc=j) / 1 (qc=63-j)
        const int wi = idx & 511;
        const int q  = wi >> 4;
        const int hs = (wi & 15) * 4;
        const float* Om = (const float*)(lds + c * 34816);
        const float* Lm = (const float*)(lds + 69632 + c * 512);
        float denom = 0.f, o0 = 0.f, o1 = 0.f, o2 = 0.f, o3 = 0.f;
#pragma unroll
        for (int w = 0; w < 4; w++) {
            denom += Lm[w * 32 + q];
            const float* op = Om + (size_t)(w * 32 + q) * 68 + hs;
            o0 += op[0]; o1 += op[1]; o2 += op[2]; o3 += op[3];
        }
        float inv = 1.f / denom;
        const int q0c = (c ? (63 - j) : j) * 32;
        *(float4*)(out + ((size_t)b * TT + q0c + q) * TH + hs) =
            make_float4(o0 * inv, o1 * inv, o2 * inv, o3 * inv);
    }
}

// ---------------------------------------------------------------------------
extern "C" void kernel_launch(void* const* d_in, const int* in_sizes, int n_in,
                              void* d_out, int out_size, void* d_ws, size_t ws_size,
                              hipStream_t stream) {
    const float* x  = (const float*)d_in[0];
    const float* wq = (const float*)d_in[1];
    const float* wk = (const float*)d_in[2];
    const float* wv = (const float*)d_in[3];

    char* ws = (char*)d_ws;
    bf16*  wT = (bf16*)(ws);                        // 393,216 B
    bf16*  Q  = (bf16*)(ws + 393216);               // 2 MB
    bf16*  K  = (bf16*)(ws + 2490368);              // 2 MB
    bf16*  VT = (bf16*)(ws + 4587520);              // 2 MB
    float* out = (float*)d_out;

    hipLaunchKernelGGL(prep_wT, dim3(768), dim3(256), 0, stream, wq, wk, wv, wT);
    hipLaunchKernelGGL(proj, dim3(256), dim3(512), 0, stream, x, wT, Q, K, VT);
    hipLaunchKernelGGL(attn, dim3(TB * 32), dim3(512), 0, stream, Q, K, VT, out);
}